// Round 1
// baseline (743.335 us; speedup 1.0000x reference)
//
#include <hip/hip_runtime.h>

#define EMB  1024
#define VIN  512
#define VOUT 1024
#define NH   16
#define DH   64
#define BB   8
#define LQ   512
#define LK   1024

// C[M,N] = A[M,K] @ W[K,N] + bias[N]
// BM=128, BN=64, BK=16, 256 threads, 8x4 micro per thread.
__global__ __launch_bounds__(256) void gemm_bias(const float* __restrict__ A,
                                                 const float* __restrict__ W,
                                                 const float* __restrict__ bias,
                                                 float* __restrict__ C,
                                                 int M, int N, int K)
{
    const int n0 = blockIdx.x * 64;
    const int m0 = blockIdx.y * 128;
    const int tid = threadIdx.x;
    const int tx = tid & 15;   // col group: cols n0 + tx*4 .. +3
    const int ty = tid >> 4;   // row group: rows m0 + ty*8 .. +7

    __shared__ float As[16][132];  // A^T tile, stride 132 (16B aligned, conflict-free)
    __shared__ float Bs[16][64];

    float acc[8][4];
#pragma unroll
    for (int i = 0; i < 8; ++i)
#pragma unroll
        for (int j = 0; j < 4; ++j) acc[i][j] = 0.f;

    const int numT = K >> 4;
    for (int t = 0; t < numT; ++t) {
        const int k0 = t << 4;
        // A tile 128x16 -> As transposed. 512 float4, 2 per thread.
#pragma unroll
        for (int r = 0; r < 2; ++r) {
            int f4  = r * 256 + tid;
            int row = f4 >> 2;            // 0..127
            int d0  = (f4 & 3) << 2;      // 0,4,8,12
            const float4 v = *reinterpret_cast<const float4*>(
                &A[(size_t)(m0 + row) * K + k0 + d0]);
            As[d0 + 0][row] = v.x;
            As[d0 + 1][row] = v.y;
            As[d0 + 2][row] = v.z;
            As[d0 + 3][row] = v.w;
        }
        // B tile 16x64, natural. 256 float4, 1 per thread.
        {
            int kk = tid >> 4;
            int c0 = (tid & 15) << 2;
            *reinterpret_cast<float4*>(&Bs[kk][c0]) =
                *reinterpret_cast<const float4*>(&W[(size_t)(k0 + kk) * N + n0 + c0]);
        }
        __syncthreads();
#pragma unroll
        for (int kk = 0; kk < 16; ++kk) {
            float a0[4], a1[4], b0[4];
            *reinterpret_cast<float4*>(a0) = *reinterpret_cast<const float4*>(&As[kk][ty * 8]);
            *reinterpret_cast<float4*>(a1) = *reinterpret_cast<const float4*>(&As[kk][ty * 8 + 4]);
            *reinterpret_cast<float4*>(b0) = *reinterpret_cast<const float4*>(&Bs[kk][tx * 4]);
#pragma unroll
            for (int i = 0; i < 4; ++i)
#pragma unroll
                for (int j = 0; j < 4; ++j) {
                    acc[i][j]     += a0[i] * b0[j];
                    acc[i + 4][j] += a1[i] * b0[j];
                }
        }
        __syncthreads();
    }

    float bl[4];
    *reinterpret_cast<float4*>(bl) = *reinterpret_cast<const float4*>(&bias[n0 + tx * 4]);
#pragma unroll
    for (int i = 0; i < 8; ++i) {
        float4 v;
        v.x = acc[i][0] + bl[0];
        v.y = acc[i][1] + bl[1];
        v.z = acc[i][2] + bl[2];
        v.w = acc[i][3] + bl[3];
        *reinterpret_cast<float4*>(&C[(size_t)(m0 + ty * 8 + i) * N + n0 + tx * 4]) = v;
    }
}

// Flash-style attention. One block per (q-tile of 64, head, batch).
// Qp [B*LQ, EMB], Kp [B*LK, EMB], Vp [B*LK, VOUT], ctx [B*LQ, VOUT].
__global__ __launch_bounds__(256) void attn_kernel(const float* __restrict__ Qp,
                                                   const float* __restrict__ Kp,
                                                   const float* __restrict__ Vp,
                                                   float* __restrict__ ctx)
{
    const int qt = blockIdx.x, h = blockIdx.y, b = blockIdx.z;
    const int tid = threadIdx.x;
    const int tx = tid & 15;   // k/dv col group
    const int qr = tid >> 4;   // q row group: rows qr*4 .. +3

    __shared__ float Qs[DH][68];   // Q^T (scaled), [d][q]
    __shared__ float Ks[DH][68];   // K^T, [d][k]
    __shared__ float Vs[64][68];   // V natural, [k][dv]
    __shared__ float Ps[64][68];   // P^T, [k][q]

    // Load + scale Q tile once.
    const float scale = 0.125f;  // 1/sqrt(64)
#pragma unroll
    for (int r = 0; r < 4; ++r) {
        int row = r * 16 + (tid >> 4);
        int d0  = (tid & 15) << 2;
        const float4 v = *reinterpret_cast<const float4*>(
            &Qp[(size_t)(b * LQ + qt * 64 + row) * EMB + h * DH + d0]);
        Qs[d0 + 0][row] = v.x * scale;
        Qs[d0 + 1][row] = v.y * scale;
        Qs[d0 + 2][row] = v.z * scale;
        Qs[d0 + 3][row] = v.w * scale;
    }

    float m[4], l[4], acc[4][4];
#pragma unroll
    for (int i = 0; i < 4; ++i) {
        m[i] = -1e30f;
        l[i] = 0.f;
#pragma unroll
        for (int j = 0; j < 4; ++j) acc[i][j] = 0.f;
    }
    __syncthreads();

    for (int kt = 0; kt < LK / 64; ++kt) {
        // Stage K (transposed) and V (natural) tiles.
#pragma unroll
        for (int r = 0; r < 4; ++r) {
            int row = r * 16 + (tid >> 4);
            int d0  = (tid & 15) << 2;
            const float4 kv = *reinterpret_cast<const float4*>(
                &Kp[(size_t)(b * LK + kt * 64 + row) * EMB + h * DH + d0]);
            Ks[d0 + 0][row] = kv.x;
            Ks[d0 + 1][row] = kv.y;
            Ks[d0 + 2][row] = kv.z;
            Ks[d0 + 3][row] = kv.w;
            const float4 vv = *reinterpret_cast<const float4*>(
                &Vp[(size_t)(b * LK + kt * 64 + row) * VOUT + h * DH + d0]);
            *reinterpret_cast<float4*>(&Vs[row][d0]) = vv;
        }
        __syncthreads();

        // Scores: s[i][j] = q_row(qr*4+i) . k_col(tx*4+j)
        float s[4][4];
#pragma unroll
        for (int i = 0; i < 4; ++i)
#pragma unroll
            for (int j = 0; j < 4; ++j) s[i][j] = 0.f;
#pragma unroll 8
        for (int d = 0; d < DH; ++d) {
            float qv[4], kv[4];
            *reinterpret_cast<float4*>(qv) = *reinterpret_cast<const float4*>(&Qs[d][qr * 4]);
            *reinterpret_cast<float4*>(kv) = *reinterpret_cast<const float4*>(&Ks[d][tx * 4]);
#pragma unroll
            for (int i = 0; i < 4; ++i)
#pragma unroll
                for (int j = 0; j < 4; ++j) s[i][j] += qv[i] * kv[j];
        }

        // Online softmax (row groups of 16 lanes).
#pragma unroll
        for (int i = 0; i < 4; ++i) {
            float mx = fmaxf(fmaxf(s[i][0], s[i][1]), fmaxf(s[i][2], s[i][3]));
            mx = fmaxf(mx, __shfl_xor(mx, 1));
            mx = fmaxf(mx, __shfl_xor(mx, 2));
            mx = fmaxf(mx, __shfl_xor(mx, 4));
            mx = fmaxf(mx, __shfl_xor(mx, 8));
            float mnew = fmaxf(m[i], mx);
            float corr = __expf(m[i] - mnew);
            float rs = 0.f;
#pragma unroll
            for (int j = 0; j < 4; ++j) {
                s[i][j] = __expf(s[i][j] - mnew);
                rs += s[i][j];
            }
            rs += __shfl_xor(rs, 1);
            rs += __shfl_xor(rs, 2);
            rs += __shfl_xor(rs, 4);
            rs += __shfl_xor(rs, 8);
            l[i] = l[i] * corr + rs;
            m[i] = mnew;
#pragma unroll
            for (int j = 0; j < 4; ++j) acc[i][j] *= corr;
        }

        // P^T to LDS for the PV contraction.
#pragma unroll
        for (int j = 0; j < 4; ++j)
#pragma unroll
            for (int i = 0; i < 4; ++i)
                Ps[tx * 4 + j][qr * 4 + i] = s[i][j];
        __syncthreads();

        // PV: acc[i][j] += sum_k P[k][q] * V[k][dv]
#pragma unroll 8
        for (int k = 0; k < 64; ++k) {
            float pv[4], vv[4];
            *reinterpret_cast<float4*>(pv) = *reinterpret_cast<const float4*>(&Ps[k][qr * 4]);
            *reinterpret_cast<float4*>(vv) = *reinterpret_cast<const float4*>(&Vs[k][tx * 4]);
#pragma unroll
            for (int i = 0; i < 4; ++i)
#pragma unroll
                for (int j = 0; j < 4; ++j) acc[i][j] += pv[i] * vv[j];
        }
        __syncthreads();
    }

    // Normalize and write ctx.
#pragma unroll
    for (int i = 0; i < 4; ++i) {
        float inv = 1.f / l[i];
        float4 v;
        v.x = acc[i][0] * inv;
        v.y = acc[i][1] * inv;
        v.z = acc[i][2] * inv;
        v.w = acc[i][3] * inv;
        *reinterpret_cast<float4*>(
            &ctx[(size_t)(b * LQ + qt * 64 + qr * 4 + i) * VOUT + h * DH + tx * 4]) = v;
    }
}

extern "C" void kernel_launch(void* const* d_in, const int* in_sizes, int n_in,
                              void* d_out, int out_size, void* d_ws, size_t ws_size,
                              hipStream_t stream)
{
    const float* query = (const float*)d_in[0];
    const float* key   = (const float*)d_in[1];
    const float* value = (const float*)d_in[2];
    const float* Wq = (const float*)d_in[3];
    const float* bq = (const float*)d_in[4];
    const float* Wk = (const float*)d_in[5];
    const float* bk = (const float*)d_in[6];
    const float* Wv = (const float*)d_in[7];
    const float* bv = (const float*)d_in[8];
    const float* Wo = (const float*)d_in[9];
    const float* bo = (const float*)d_in[10];
    float* out = (float*)d_out;

    // Workspace layout (96 MB total):
    float* Qp  = (float*)d_ws;                    // [4096,1024]  16 MB
    float* Kp  = Qp  + (size_t)BB * LQ * EMB;     // [8192,1024]  32 MB
    float* Vp  = Kp  + (size_t)BB * LK * EMB;     // [8192,1024]  32 MB
    float* ctx = Vp  + (size_t)BB * LK * VOUT;    // [4096,1024]  16 MB

    // Projections.
    gemm_bias<<<dim3(EMB / 64,  BB * LQ / 128), 256, 0, stream>>>(query, Wq, bq, Qp,  BB * LQ, EMB,  EMB);
    gemm_bias<<<dim3(EMB / 64,  BB * LK / 128), 256, 0, stream>>>(key,   Wk, bk, Kp,  BB * LK, EMB,  VIN);
    gemm_bias<<<dim3(VOUT / 64, BB * LK / 128), 256, 0, stream>>>(value, Wv, bv, Vp,  BB * LK, VOUT, VIN);

    // Attention.
    attn_kernel<<<dim3(LQ / 64, NH, BB), 256, 0, stream>>>(Qp, Kp, Vp, ctx);

    // Output projection.
    gemm_bias<<<dim3(EMB / 64,  BB * LQ / 128), 256, 0, stream>>>(ctx, Wo, bo, out, BB * LQ, EMB, VOUT);
}

// Round 2
// 503.897 us; speedup vs baseline: 1.4752x; 1.4752x over previous
//
#include <hip/hip_runtime.h>

#define EMB  1024
#define VIN  512
#define VOUT 1024
#define NH   16
#define DH   64
#define BB   8
#define LQ   512
#define LK   1024

typedef __attribute__((ext_vector_type(8))) short bf16x8;
typedef __attribute__((ext_vector_type(4))) float f32x4;

__device__ __forceinline__ unsigned short f2bf(float x) {
    unsigned int u = __float_as_uint(x);
    u += 0x7FFF + ((u >> 16) & 1);   // RN-even
    return (unsigned short)(u >> 16);
}
__device__ __forceinline__ float bf2f(unsigned short h) {
    return __uint_as_float(((unsigned int)h) << 16);
}

// ---------------------------------------------------------------------------
// W [K,N] fp32 -> Wht, Wlt [N,K] bf16 hi/lo planes (transposed split).
// ---------------------------------------------------------------------------
__global__ __launch_bounds__(256) void wsplit_t(const float* __restrict__ W,
                                                unsigned short* __restrict__ Wht,
                                                unsigned short* __restrict__ Wlt,
                                                int K, int N)
{
    __shared__ float t[32][33];
    const int n0 = blockIdx.x * 32, k0 = blockIdx.y * 32;
    const int tx = threadIdx.x, ty = threadIdx.y;  // 32 x 8
#pragma unroll
    for (int r = 0; r < 32; r += 8)
        t[ty + r][tx] = W[(size_t)(k0 + ty + r) * N + n0 + tx];
    __syncthreads();
#pragma unroll
    for (int r = 0; r < 32; r += 8) {
        float x = t[tx][ty + r];                 // W[k0+tx][n0+ty+r]
        unsigned short h = f2bf(x);
        unsigned short l = f2bf(x - bf2f(h));
        size_t o = (size_t)(n0 + ty + r) * K + k0 + tx;
        Wht[o] = h;
        Wlt[o] = l;
    }
}

// ---------------------------------------------------------------------------
// Split-bf16 MFMA GEMM: C[M,N] = A[M,K](fp32) @ W[K,N] + bias
// W given as transposed bf16 hi/lo planes [N,K]. BM=BN=128, BK=64.
// 256 threads = 4 waves (2x2), each wave 64x64 = 4x4 frags of 16x16x32.
// ---------------------------------------------------------------------------
#define SWZ(row, cb) (((row) << 7) + ((cb) ^ (((row) & 7) << 4)))

__global__ __launch_bounds__(256, 2) void gemm_split(const float* __restrict__ A,
                                                     const unsigned short* __restrict__ Bht,
                                                     const unsigned short* __restrict__ Blt,
                                                     const float* __restrict__ bias,
                                                     float* __restrict__ C,
                                                     int M, int N, int K)
{
    __shared__ unsigned short As_h[128 * 64], As_l[128 * 64];
    __shared__ unsigned short Bs_h[128 * 64], Bs_l[128 * 64];

    const int nbx = N >> 7;
    const int nwg = gridDim.x;
    const int qq  = nwg >> 3;
    const int id  = blockIdx.x;
    const int swz = (id & 7) * qq + (id >> 3);   // XCD-aware (nwg % 8 == 0)
    const int bx = swz % nbx, by = swz / nbx;
    const int m0 = by * 128, n0 = bx * 128;

    const int tid  = threadIdx.x;
    const int lane = tid & 63;
    const int wid  = tid >> 6;
    const int wm = (wid & 1) * 64;
    const int wn = (wid >> 1) * 64;
    const int lr = lane & 15;
    const int lk = lane >> 4;

    f32x4 acc[4][4];
#pragma unroll
    for (int i = 0; i < 4; ++i)
#pragma unroll
        for (int j = 0; j < 4; ++j) acc[i][j] = (f32x4)(0.f);

    float4 ast[8];
    int4   bsth[4], bstl[4];

    const int nt = K >> 6;

    // prologue: load tile 0
    {
        const int k0 = 0;
#pragma unroll
        for (int r = 0; r < 8; ++r) {
            int i = r * 256 + tid, row = i >> 4, c4 = i & 15;
            ast[r] = *reinterpret_cast<const float4*>(&A[(size_t)(m0 + row) * K + k0 + c4 * 4]);
        }
#pragma unroll
        for (int r = 0; r < 4; ++r) {
            int i = r * 256 + tid, row = i >> 3, c16 = i & 7;
            size_t o = (size_t)(n0 + row) * K + k0 + c16 * 8;
            bsth[r] = *reinterpret_cast<const int4*>(&Bht[o]);
            bstl[r] = *reinterpret_cast<const int4*>(&Blt[o]);
        }
    }

    for (int t = 0; t < nt; ++t) {
        __syncthreads();
        // stage regs -> LDS (convert A to hi/lo here)
#pragma unroll
        for (int r = 0; r < 8; ++r) {
            int i = r * 256 + tid, row = i >> 4, c4 = i & 15;
            float v[4];
            *reinterpret_cast<float4*>(v) = ast[r];
            ushort h[4], l[4];
#pragma unroll
            for (int j = 0; j < 4; ++j) {
                h[j] = f2bf(v[j]);
                l[j] = f2bf(v[j] - bf2f(h[j]));
            }
            int off = SWZ(row, c4 * 8);
            *reinterpret_cast<uint2*>((char*)As_h + off) = *reinterpret_cast<uint2*>(h);
            *reinterpret_cast<uint2*>((char*)As_l + off) = *reinterpret_cast<uint2*>(l);
        }
#pragma unroll
        for (int r = 0; r < 4; ++r) {
            int i = r * 256 + tid, row = i >> 3, c16 = i & 7;
            int off = SWZ(row, c16 * 16);
            *reinterpret_cast<int4*>((char*)Bs_h + off) = bsth[r];
            *reinterpret_cast<int4*>((char*)Bs_l + off) = bstl[r];
        }
        __syncthreads();

        // prefetch next tile into regs (in flight during compute)
        if (t + 1 < nt) {
            const int k0 = (t + 1) << 6;
#pragma unroll
            for (int r = 0; r < 8; ++r) {
                int i = r * 256 + tid, row = i >> 4, c4 = i & 15;
                ast[r] = *reinterpret_cast<const float4*>(&A[(size_t)(m0 + row) * K + k0 + c4 * 4]);
            }
#pragma unroll
            for (int r = 0; r < 4; ++r) {
                int i = r * 256 + tid, row = i >> 3, c16 = i & 7;
                size_t o = (size_t)(n0 + row) * K + k0 + c16 * 8;
                bsth[r] = *reinterpret_cast<const int4*>(&Bht[o]);
                bstl[r] = *reinterpret_cast<const int4*>(&Blt[o]);
            }
        }

        // compute: 2 k-steps, 48 MFMA each
#pragma unroll
        for (int ks = 0; ks < 2; ++ks) {
            bf16x8 ah[4], al[4], bh[4], bl[4];
            const int cb = ks * 64 + lk * 16;
#pragma unroll
            for (int f = 0; f < 4; ++f) {
                int rowA = wm + f * 16 + lr;
                ah[f] = *reinterpret_cast<const bf16x8*>((char*)As_h + SWZ(rowA, cb));
                al[f] = *reinterpret_cast<const bf16x8*>((char*)As_l + SWZ(rowA, cb));
                int rowB = wn + f * 16 + lr;
                bh[f] = *reinterpret_cast<const bf16x8*>((char*)Bs_h + SWZ(rowB, cb));
                bl[f] = *reinterpret_cast<const bf16x8*>((char*)Bs_l + SWZ(rowB, cb));
            }
#pragma unroll
            for (int fm = 0; fm < 4; ++fm)
#pragma unroll
                for (int fn = 0; fn < 4; ++fn) {
                    acc[fm][fn] = __builtin_amdgcn_mfma_f32_16x16x32_bf16(ah[fm], bh[fn], acc[fm][fn], 0, 0, 0);
                    acc[fm][fn] = __builtin_amdgcn_mfma_f32_16x16x32_bf16(ah[fm], bl[fn], acc[fm][fn], 0, 0, 0);
                    acc[fm][fn] = __builtin_amdgcn_mfma_f32_16x16x32_bf16(al[fm], bh[fn], acc[fm][fn], 0, 0, 0);
                }
        }
    }

    // epilogue: bias + store (C/D layout: col = lane&15, row = (lane>>4)*4 + reg)
#pragma unroll
    for (int fn = 0; fn < 4; ++fn) {
        const float bv = bias[n0 + wn + fn * 16 + lr];
#pragma unroll
        for (int fm = 0; fm < 4; ++fm) {
#pragma unroll
            for (int r = 0; r < 4; ++r) {
                int row = m0 + wm + fm * 16 + lk * 4 + r;
                int col = n0 + wn + fn * 16 + lr;
                C[(size_t)row * N + col] = acc[fm][fn][r] + bv;
            }
        }
    }
}

// ---------------------------------------------------------------------------
// Flash-style fp32 attention (unchanged from R1 except ctx may alias Qp:
// each block reads only its own Qp rows x head-cols into LDS before the first
// barrier, and writes the identical ctx region only at the very end).
// ---------------------------------------------------------------------------
__global__ __launch_bounds__(256) void attn_kernel(const float* Qp,
                                                   const float* __restrict__ Kp,
                                                   const float* __restrict__ Vp,
                                                   float* ctx)
{
    const int qt = blockIdx.x, h = blockIdx.y, b = blockIdx.z;
    const int tid = threadIdx.x;
    const int tx = tid & 15;
    const int qr = tid >> 4;

    __shared__ float Qs[DH][68];
    __shared__ float Ks[DH][68];
    __shared__ float Vs[64][68];
    __shared__ float Ps[64][68];

    const float scale = 0.125f;
#pragma unroll
    for (int r = 0; r < 4; ++r) {
        int row = r * 16 + (tid >> 4);
        int d0  = (tid & 15) << 2;
        const float4 v = *reinterpret_cast<const float4*>(
            &Qp[(size_t)(b * LQ + qt * 64 + row) * EMB + h * DH + d0]);
        Qs[d0 + 0][row] = v.x * scale;
        Qs[d0 + 1][row] = v.y * scale;
        Qs[d0 + 2][row] = v.z * scale;
        Qs[d0 + 3][row] = v.w * scale;
    }

    float m[4], l[4], acc[4][4];
#pragma unroll
    for (int i = 0; i < 4; ++i) {
        m[i] = -1e30f;
        l[i] = 0.f;
#pragma unroll
        for (int j = 0; j < 4; ++j) acc[i][j] = 0.f;
    }
    __syncthreads();

    for (int kt = 0; kt < LK / 64; ++kt) {
#pragma unroll
        for (int r = 0; r < 4; ++r) {
            int row = r * 16 + (tid >> 4);
            int d0  = (tid & 15) << 2;
            const float4 kv = *reinterpret_cast<const float4*>(
                &Kp[(size_t)(b * LK + kt * 64 + row) * EMB + h * DH + d0]);
            Ks[d0 + 0][row] = kv.x;
            Ks[d0 + 1][row] = kv.y;
            Ks[d0 + 2][row] = kv.z;
            Ks[d0 + 3][row] = kv.w;
            const float4 vv = *reinterpret_cast<const float4*>(
                &Vp[(size_t)(b * LK + kt * 64 + row) * VOUT + h * DH + d0]);
            *reinterpret_cast<float4*>(&Vs[row][d0]) = vv;
        }
        __syncthreads();

        float s[4][4];
#pragma unroll
        for (int i = 0; i < 4; ++i)
#pragma unroll
            for (int j = 0; j < 4; ++j) s[i][j] = 0.f;
#pragma unroll 8
        for (int d = 0; d < DH; ++d) {
            float qv[4], kv[4];
            *reinterpret_cast<float4*>(qv) = *reinterpret_cast<const float4*>(&Qs[d][qr * 4]);
            *reinterpret_cast<float4*>(kv) = *reinterpret_cast<const float4*>(&Ks[d][tx * 4]);
#pragma unroll
            for (int i = 0; i < 4; ++i)
#pragma unroll
                for (int j = 0; j < 4; ++j) s[i][j] += qv[i] * kv[j];
        }

#pragma unroll
        for (int i = 0; i < 4; ++i) {
            float mx = fmaxf(fmaxf(s[i][0], s[i][1]), fmaxf(s[i][2], s[i][3]));
            mx = fmaxf(mx, __shfl_xor(mx, 1));
            mx = fmaxf(mx, __shfl_xor(mx, 2));
            mx = fmaxf(mx, __shfl_xor(mx, 4));
            mx = fmaxf(mx, __shfl_xor(mx, 8));
            float mnew = fmaxf(m[i], mx);
            float corr = __expf(m[i] - mnew);
            float rs = 0.f;
#pragma unroll
            for (int j = 0; j < 4; ++j) {
                s[i][j] = __expf(s[i][j] - mnew);
                rs += s[i][j];
            }
            rs += __shfl_xor(rs, 1);
            rs += __shfl_xor(rs, 2);
            rs += __shfl_xor(rs, 4);
            rs += __shfl_xor(rs, 8);
            l[i] = l[i] * corr + rs;
            m[i] = mnew;
#pragma unroll
            for (int j = 0; j < 4; ++j) acc[i][j] *= corr;
        }

#pragma unroll
        for (int j = 0; j < 4; ++j)
#pragma unroll
            for (int i = 0; i < 4; ++i)
                Ps[tx * 4 + j][qr * 4 + i] = s[i][j];
        __syncthreads();

#pragma unroll 8
        for (int k = 0; k < 64; ++k) {
            float pv[4], vv[4];
            *reinterpret_cast<float4*>(pv) = *reinterpret_cast<const float4*>(&Ps[k][qr * 4]);
            *reinterpret_cast<float4*>(vv) = *reinterpret_cast<const float4*>(&Vs[k][tx * 4]);
#pragma unroll
            for (int i = 0; i < 4; ++i)
#pragma unroll
                for (int j = 0; j < 4; ++j) acc[i][j] += pv[i] * vv[j];
        }
        __syncthreads();
    }

#pragma unroll
    for (int i = 0; i < 4; ++i) {
        float inv = 1.f / l[i];
        float4 v;
        v.x = acc[i][0] * inv;
        v.y = acc[i][1] * inv;
        v.z = acc[i][2] * inv;
        v.w = acc[i][3] * inv;
        *reinterpret_cast<float4*>(
            &ctx[(size_t)(b * LQ + qt * 64 + qr * 4 + i) * VOUT + h * DH + tx * 4]) = v;
    }
}

extern "C" void kernel_launch(void* const* d_in, const int* in_sizes, int n_in,
                              void* d_out, int out_size, void* d_ws, size_t ws_size,
                              hipStream_t stream)
{
    const float* query = (const float*)d_in[0];
    const float* key   = (const float*)d_in[1];
    const float* value = (const float*)d_in[2];
    const float* Wq = (const float*)d_in[3];
    const float* bq = (const float*)d_in[4];
    const float* Wk = (const float*)d_in[5];
    const float* bk = (const float*)d_in[6];
    const float* Wv = (const float*)d_in[7];
    const float* bv = (const float*)d_in[8];
    const float* Wo = (const float*)d_in[9];
    const float* bo = (const float*)d_in[10];
    float* out = (float*)d_out;

    // Workspace: [Qp/ctx 16MB][Kp 32MB][Vp 32MB][W split 4MB] = 84 MB
    float* Qp = (float*)d_ws;
    float* Kp = Qp + (size_t)BB * LQ * EMB;
    float* Vp = Kp + (size_t)BB * LK * EMB;
    unsigned short* Wht = (unsigned short*)(Vp + (size_t)BB * LK * VOUT);
    unsigned short* Wlt = Wht + (size_t)EMB * EMB;

    // Q projection: A[4096,1024] @ Wq[1024,1024]
    wsplit_t<<<dim3(EMB / 32, EMB / 32), dim3(32, 8), 0, stream>>>(Wq, Wht, Wlt, EMB, EMB);
    gemm_split<<<(EMB / 128) * (BB * LQ / 128), 256, 0, stream>>>(query, Wht, Wlt, bq, Qp, BB * LQ, EMB, EMB);

    // K projection: A[8192,512] @ Wk[512,1024]
    wsplit_t<<<dim3(EMB / 32, VIN / 32), dim3(32, 8), 0, stream>>>(Wk, Wht, Wlt, VIN, EMB);
    gemm_split<<<(EMB / 128) * (BB * LK / 128), 256, 0, stream>>>(key, Wht, Wlt, bk, Kp, BB * LK, EMB, VIN);

    // V projection: A[8192,512] @ Wv[512,1024]
    wsplit_t<<<dim3(VOUT / 32, VIN / 32), dim3(32, 8), 0, stream>>>(Wv, Wht, Wlt, VIN, VOUT);
    gemm_split<<<(VOUT / 128) * (BB * LK / 128), 256, 0, stream>>>(value, Wht, Wlt, bv, Vp, BB * LK, VOUT, VIN);

    // Attention (ctx written in-place over Qp; per-block regions disjoint)
    attn_kernel<<<dim3(LQ / 64, NH, BB), 256, 0, stream>>>(Qp, Kp, Vp, Qp);

    // Output projection: ctx[4096,1024] @ Wo[1024,1024]
    wsplit_t<<<dim3(EMB / 32, VOUT / 32), dim3(32, 8), 0, stream>>>(Wo, Wht, Wlt, VOUT, EMB);
    gemm_split<<<(EMB / 128) * (BB * LQ / 128), 256, 0, stream>>>(Qp, Wht, Wlt, bo, out, BB * LQ, EMB, VOUT);
}

// Round 3
// 355.334 us; speedup vs baseline: 2.0919x; 1.4181x over previous
//
#include <hip/hip_runtime.h>

#define EMB  1024
#define VIN  512
#define VOUT 1024
#define NH   16
#define DH   64
#define BB   8
#define LQ   512
#define LK   1024

typedef __attribute__((ext_vector_type(8))) short bf16x8;
typedef __attribute__((ext_vector_type(4))) float f32x4;

__device__ __forceinline__ unsigned short f2bf(float x) {
    unsigned int u = __float_as_uint(x);
    u += 0x7FFF + ((u >> 16) & 1);   // RN-even
    return (unsigned short)(u >> 16);
}
__device__ __forceinline__ float bf2f(unsigned short h) {
    return __uint_as_float(((unsigned int)h) << 16);
}

#define SWZ(row, cb) (((row) << 7) + ((cb) ^ (((row) & 7) << 4)))

// ---------------------------------------------------------------------------
// W [K,N] fp32 -> Wht, Wlt [N,K] bf16 hi/lo planes (transposed split).
// ---------------------------------------------------------------------------
__global__ __launch_bounds__(256) void wsplit_t(const float* __restrict__ W,
                                                unsigned short* __restrict__ Wht,
                                                unsigned short* __restrict__ Wlt,
                                                int K, int N)
{
    __shared__ float t[32][33];
    const int n0 = blockIdx.x * 32, k0 = blockIdx.y * 32;
    const int tx = threadIdx.x, ty = threadIdx.y;  // 32 x 8
#pragma unroll
    for (int r = 0; r < 32; r += 8)
        t[ty + r][tx] = W[(size_t)(k0 + ty + r) * N + n0 + tx];
    __syncthreads();
#pragma unroll
    for (int r = 0; r < 32; r += 8) {
        float x = t[tx][ty + r];                 // W[k0+tx][n0+ty+r]
        unsigned short h = f2bf(x);
        unsigned short l = f2bf(x - bf2f(h));
        size_t o = (size_t)(n0 + ty + r) * K + k0 + tx;
        Wht[o] = h;
        Wlt[o] = l;
    }
}

// ---------------------------------------------------------------------------
// Split-bf16 MFMA GEMM (unchanged from R2): C = A(fp32) @ W + bias
// ---------------------------------------------------------------------------
__global__ __launch_bounds__(256, 2) void gemm_split(const float* __restrict__ A,
                                                     const unsigned short* __restrict__ Bht,
                                                     const unsigned short* __restrict__ Blt,
                                                     const float* __restrict__ bias,
                                                     float* __restrict__ C,
                                                     int M, int N, int K)
{
    __shared__ unsigned short As_h[128 * 64], As_l[128 * 64];
    __shared__ unsigned short Bs_h[128 * 64], Bs_l[128 * 64];

    const int nbx = N >> 7;
    const int nwg = gridDim.x;
    const int qq  = nwg >> 3;
    const int id  = blockIdx.x;
    const int swz = (id & 7) * qq + (id >> 3);   // XCD-aware (nwg % 8 == 0)
    const int bx = swz % nbx, by = swz / nbx;
    const int m0 = by * 128, n0 = bx * 128;

    const int tid  = threadIdx.x;
    const int lane = tid & 63;
    const int wid  = tid >> 6;
    const int wm = (wid & 1) * 64;
    const int wn = (wid >> 1) * 64;
    const int lr = lane & 15;
    const int lk = lane >> 4;

    f32x4 acc[4][4];
#pragma unroll
    for (int i = 0; i < 4; ++i)
#pragma unroll
        for (int j = 0; j < 4; ++j) acc[i][j] = (f32x4)(0.f);

    float4 ast[8];
    int4   bsth[4], bstl[4];

    const int nt = K >> 6;

    {
#pragma unroll
        for (int r = 0; r < 8; ++r) {
            int i = r * 256 + tid, row = i >> 4, c4 = i & 15;
            ast[r] = *reinterpret_cast<const float4*>(&A[(size_t)(m0 + row) * K + c4 * 4]);
        }
#pragma unroll
        for (int r = 0; r < 4; ++r) {
            int i = r * 256 + tid, row = i >> 3, c16 = i & 7;
            size_t o = (size_t)(n0 + row) * K + c16 * 8;
            bsth[r] = *reinterpret_cast<const int4*>(&Bht[o]);
            bstl[r] = *reinterpret_cast<const int4*>(&Blt[o]);
        }
    }

    for (int t = 0; t < nt; ++t) {
        __syncthreads();
#pragma unroll
        for (int r = 0; r < 8; ++r) {
            int i = r * 256 + tid, row = i >> 4, c4 = i & 15;
            float v[4];
            *reinterpret_cast<float4*>(v) = ast[r];
            ushort h[4], l[4];
#pragma unroll
            for (int j = 0; j < 4; ++j) {
                h[j] = f2bf(v[j]);
                l[j] = f2bf(v[j] - bf2f(h[j]));
            }
            int off = SWZ(row, c4 * 8);
            *reinterpret_cast<uint2*>((char*)As_h + off) = *reinterpret_cast<uint2*>(h);
            *reinterpret_cast<uint2*>((char*)As_l + off) = *reinterpret_cast<uint2*>(l);
        }
#pragma unroll
        for (int r = 0; r < 4; ++r) {
            int i = r * 256 + tid, row = i >> 3, c16 = i & 7;
            int off = SWZ(row, c16 * 16);
            *reinterpret_cast<int4*>((char*)Bs_h + off) = bsth[r];
            *reinterpret_cast<int4*>((char*)Bs_l + off) = bstl[r];
        }
        __syncthreads();

        if (t + 1 < nt) {
            const int k0 = (t + 1) << 6;
#pragma unroll
            for (int r = 0; r < 8; ++r) {
                int i = r * 256 + tid, row = i >> 4, c4 = i & 15;
                ast[r] = *reinterpret_cast<const float4*>(&A[(size_t)(m0 + row) * K + k0 + c4 * 4]);
            }
#pragma unroll
            for (int r = 0; r < 4; ++r) {
                int i = r * 256 + tid, row = i >> 3, c16 = i & 7;
                size_t o = (size_t)(n0 + row) * K + k0 + c16 * 8;
                bsth[r] = *reinterpret_cast<const int4*>(&Bht[o]);
                bstl[r] = *reinterpret_cast<const int4*>(&Blt[o]);
            }
        }

#pragma unroll
        for (int ks = 0; ks < 2; ++ks) {
            bf16x8 ah[4], al[4], bh[4], bl[4];
            const int cb = ks * 64 + lk * 16;
#pragma unroll
            for (int f = 0; f < 4; ++f) {
                int rowA = wm + f * 16 + lr;
                ah[f] = *reinterpret_cast<const bf16x8*>((char*)As_h + SWZ(rowA, cb));
                al[f] = *reinterpret_cast<const bf16x8*>((char*)As_l + SWZ(rowA, cb));
                int rowB = wn + f * 16 + lr;
                bh[f] = *reinterpret_cast<const bf16x8*>((char*)Bs_h + SWZ(rowB, cb));
                bl[f] = *reinterpret_cast<const bf16x8*>((char*)Bs_l + SWZ(rowB, cb));
            }
#pragma unroll
            for (int fm = 0; fm < 4; ++fm)
#pragma unroll
                for (int fn = 0; fn < 4; ++fn) {
                    acc[fm][fn] = __builtin_amdgcn_mfma_f32_16x16x32_bf16(ah[fm], bh[fn], acc[fm][fn], 0, 0, 0);
                    acc[fm][fn] = __builtin_amdgcn_mfma_f32_16x16x32_bf16(ah[fm], bl[fn], acc[fm][fn], 0, 0, 0);
                    acc[fm][fn] = __builtin_amdgcn_mfma_f32_16x16x32_bf16(al[fm], bh[fn], acc[fm][fn], 0, 0, 0);
                }
        }
    }

#pragma unroll
    for (int fn = 0; fn < 4; ++fn) {
        const float bv = bias[n0 + wn + fn * 16 + lr];
#pragma unroll
        for (int fm = 0; fm < 4; ++fm) {
#pragma unroll
            for (int r = 0; r < 4; ++r) {
                int row = m0 + wm + fm * 16 + lk * 4 + r;
                int col = n0 + wn + fn * 16 + lr;
                C[(size_t)row * N + col] = acc[fm][fn][r] + bv;
            }
        }
    }
}

// ---------------------------------------------------------------------------
// MFMA flash attention, split-bf16 on both QK^T and PV (fp32-grade).
// Block = (q-tile 64, head, batch); 4 waves; wave w owns q-rows w*16..+15.
// KV tiles of 64 keys, reg-prefetched, LDS-staged with XOR swizzle.
// ctx may alias Qp: block reads its exact Q region into regs before any write.
// ---------------------------------------------------------------------------
__global__ __launch_bounds__(256, 2) void attn_mfma(const float* Qp,
                                                    const float* __restrict__ Kp,
                                                    const float* __restrict__ Vp,
                                                    float* ctx)
{
    const int qt = blockIdx.x, h = blockIdx.y, b = blockIdx.z;
    const int tid  = threadIdx.x;
    const int lane = tid & 63;
    const int w    = tid >> 6;
    const int lr   = lane & 15;
    const int lk   = lane >> 4;

    __shared__ unsigned short Ks_h[64 * 64], Ks_l[64 * 64];   // [key][d]
    __shared__ unsigned short Vs_h[64 * 64], Vs_l[64 * 64];   // [dv][key] (transposed)
    __shared__ unsigned short Ps_h[4][16 * 64], Ps_l[4][16 * 64];  // per-wave [q][key]

    // --- Q fragments (scaled + split), rows w*16 + lr -----------------------
    bf16x8 qh[2], ql[2];
    {
        const float scale = 0.125f;  // 1/sqrt(64)
        const float* qrow = &Qp[(size_t)(b * LQ + qt * 64 + w * 16 + lr) * EMB + h * DH];
#pragma unroll
        for (int ks = 0; ks < 2; ++ks) {
            float v[8];
            *reinterpret_cast<float4*>(v)     = *reinterpret_cast<const float4*>(&qrow[ks * 32 + lk * 8]);
            *reinterpret_cast<float4*>(v + 4) = *reinterpret_cast<const float4*>(&qrow[ks * 32 + lk * 8 + 4]);
            ushort hh[8], ll[8];
#pragma unroll
            for (int e = 0; e < 8; ++e) {
                float x = v[e] * scale;
                hh[e] = f2bf(x);
                ll[e] = f2bf(x - bf2f(hh[e]));
            }
            qh[ks] = *reinterpret_cast<bf16x8*>(hh);
            ql[ks] = *reinterpret_cast<bf16x8*>(ll);
        }
    }

    const float* Kbase = &Kp[(size_t)(b * LK) * EMB + h * DH];
    const float* Vbase = &Vp[(size_t)(b * LK) * VOUT + h * DH];

    float4 kreg[4], vreg[4];
    const int vk0  = (tid >> 4) * 4;   // V k-block
    const int vdv0 = (tid & 15) * 4;   // V dv-block

    // prefetch tile 0
#pragma unroll
    for (int r = 0; r < 4; ++r) {
        int i = r * 256 + tid;
        kreg[r] = *reinterpret_cast<const float4*>(&Kbase[(size_t)(i >> 4) * EMB + (i & 15) * 4]);
    }
#pragma unroll
    for (int j = 0; j < 4; ++j)
        vreg[j] = *reinterpret_cast<const float4*>(&Vbase[(size_t)(vk0 + j) * VOUT + vdv0]);

    float m[4], lsum[4];
    f32x4 acc[4];
#pragma unroll
    for (int r = 0; r < 4; ++r) { m[r] = -1e30f; lsum[r] = 0.f; }
#pragma unroll
    for (int f = 0; f < 4; ++f) acc[f] = (f32x4)(0.f);

    for (int kt = 0; kt < LK / 64; ++kt) {
        __syncthreads();
        // stage K (split) ----------------------------------------------------
#pragma unroll
        for (int r = 0; r < 4; ++r) {
            int i = r * 256 + tid, row = i >> 4, cb = (i & 15) * 8;
            float v[4];
            *reinterpret_cast<float4*>(v) = kreg[r];
            ushort hh[4], ll[4];
#pragma unroll
            for (int j = 0; j < 4; ++j) {
                hh[j] = f2bf(v[j]);
                ll[j] = f2bf(v[j] - bf2f(hh[j]));
            }
            *reinterpret_cast<uint2*>((char*)Ks_h + SWZ(row, cb)) = *reinterpret_cast<uint2*>(hh);
            *reinterpret_cast<uint2*>((char*)Ks_l + SWZ(row, cb)) = *reinterpret_cast<uint2*>(ll);
        }
        // stage V transposed (split), pack 4 consecutive k per write --------
        {
            float v[4][4];
#pragma unroll
            for (int j = 0; j < 4; ++j) *reinterpret_cast<float4*>(v[j]) = vreg[j];
#pragma unroll
            for (int c = 0; c < 4; ++c) {
                ushort hh[4], ll[4];
#pragma unroll
                for (int j = 0; j < 4; ++j) {
                    float x = v[j][c];
                    hh[j] = f2bf(x);
                    ll[j] = f2bf(x - bf2f(hh[j]));
                }
                *reinterpret_cast<uint2*>((char*)Vs_h + SWZ(vdv0 + c, 2 * vk0)) = *reinterpret_cast<uint2*>(hh);
                *reinterpret_cast<uint2*>((char*)Vs_l + SWZ(vdv0 + c, 2 * vk0)) = *reinterpret_cast<uint2*>(ll);
            }
        }
        __syncthreads();

        // prefetch next tile -------------------------------------------------
        if (kt + 1 < LK / 64) {
            const size_t koff = (size_t)(kt + 1) * 64;
#pragma unroll
            for (int r = 0; r < 4; ++r) {
                int i = r * 256 + tid;
                kreg[r] = *reinterpret_cast<const float4*>(&Kbase[(koff + (i >> 4)) * EMB + (i & 15) * 4]);
            }
#pragma unroll
            for (int j = 0; j < 4; ++j)
                vreg[j] = *reinterpret_cast<const float4*>(&Vbase[(koff + vk0 + j) * VOUT + vdv0]);
        }

        // QK^T: s[fn] = 16q x 16key frags ------------------------------------
        f32x4 s[4];
#pragma unroll
        for (int fn = 0; fn < 4; ++fn) s[fn] = (f32x4)(0.f);
#pragma unroll
        for (int ks = 0; ks < 2; ++ks) {
            const int cb = ks * 64 + lk * 16;
#pragma unroll
            for (int fn = 0; fn < 4; ++fn) {
                bf16x8 kh = *reinterpret_cast<const bf16x8*>((char*)Ks_h + SWZ(fn * 16 + lr, cb));
                bf16x8 kl = *reinterpret_cast<const bf16x8*>((char*)Ks_l + SWZ(fn * 16 + lr, cb));
                s[fn] = __builtin_amdgcn_mfma_f32_16x16x32_bf16(qh[ks], kh, s[fn], 0, 0, 0);
                s[fn] = __builtin_amdgcn_mfma_f32_16x16x32_bf16(qh[ks], kl, s[fn], 0, 0, 0);
                s[fn] = __builtin_amdgcn_mfma_f32_16x16x32_bf16(ql[ks], kh, s[fn], 0, 0, 0);
            }
        }

        // online softmax (rows lk*4 + r, wave-parallel) ----------------------
#pragma unroll
        for (int r = 0; r < 4; ++r) {
            float mx = fmaxf(fmaxf(s[0][r], s[1][r]), fmaxf(s[2][r], s[3][r]));
            mx = fmaxf(mx, __shfl_xor(mx, 1));
            mx = fmaxf(mx, __shfl_xor(mx, 2));
            mx = fmaxf(mx, __shfl_xor(mx, 4));
            mx = fmaxf(mx, __shfl_xor(mx, 8));
            float mnew = fmaxf(m[r], mx);
            float corr = __expf(m[r] - mnew);
            m[r] = mnew;
            float rs = 0.f;
#pragma unroll
            for (int fn = 0; fn < 4; ++fn) {
                float p = __expf(s[fn][r] - mnew);
                s[fn][r] = p;
                rs += p;
            }
            rs += __shfl_xor(rs, 1);
            rs += __shfl_xor(rs, 2);
            rs += __shfl_xor(rs, 4);
            rs += __shfl_xor(rs, 8);
            lsum[r] = lsum[r] * corr + rs;
#pragma unroll
            for (int f = 0; f < 4; ++f) acc[f][r] *= corr;
        }

        // P (split) -> wave-private LDS, [q][key] ---------------------------
#pragma unroll
        for (int fn = 0; fn < 4; ++fn)
#pragma unroll
            for (int r = 0; r < 4; ++r) {
                float p = s[fn][r];
                ushort ph = f2bf(p);
                ushort pl = f2bf(p - bf2f(ph));
                int q = lk * 4 + r, cb = 2 * (fn * 16 + lr);
                *reinterpret_cast<ushort*>((char*)Ps_h[w] + SWZ(q, cb)) = ph;
                *reinterpret_cast<ushort*>((char*)Ps_l[w] + SWZ(q, cb)) = pl;
            }

        // PV: acc[fn2] += P @ V ---------------------------------------------
#pragma unroll
        for (int ks = 0; ks < 2; ++ks) {
            const int cb = ks * 64 + lk * 16;
            bf16x8 pa = *reinterpret_cast<const bf16x8*>((char*)Ps_h[w] + SWZ(lr, cb));
            bf16x8 pb = *reinterpret_cast<const bf16x8*>((char*)Ps_l[w] + SWZ(lr, cb));
#pragma unroll
            for (int f = 0; f < 4; ++f) {
                bf16x8 vh = *reinterpret_cast<const bf16x8*>((char*)Vs_h + SWZ(f * 16 + lr, cb));
                bf16x8 vl = *reinterpret_cast<const bf16x8*>((char*)Vs_l + SWZ(f * 16 + lr, cb));
                acc[f] = __builtin_amdgcn_mfma_f32_16x16x32_bf16(pa, vh, acc[f], 0, 0, 0);
                acc[f] = __builtin_amdgcn_mfma_f32_16x16x32_bf16(pa, vl, acc[f], 0, 0, 0);
                acc[f] = __builtin_amdgcn_mfma_f32_16x16x32_bf16(pb, vh, acc[f], 0, 0, 0);
            }
        }
    }

    // epilogue: normalize + write ctx (rows lk*4+r, cols f*16+lr) -----------
#pragma unroll
    for (int r = 0; r < 4; ++r) {
        float inv = 1.f / lsum[r];
        float* crow = &ctx[(size_t)(b * LQ + qt * 64 + w * 16 + lk * 4 + r) * VOUT + h * DH];
#pragma unroll
        for (int f = 0; f < 4; ++f)
            crow[f * 16 + lr] = acc[f][r] * inv;
    }
}

extern "C" void kernel_launch(void* const* d_in, const int* in_sizes, int n_in,
                              void* d_out, int out_size, void* d_ws, size_t ws_size,
                              hipStream_t stream)
{
    const float* query = (const float*)d_in[0];
    const float* key   = (const float*)d_in[1];
    const float* value = (const float*)d_in[2];
    const float* Wq = (const float*)d_in[3];
    const float* bq = (const float*)d_in[4];
    const float* Wk = (const float*)d_in[5];
    const float* bk = (const float*)d_in[6];
    const float* Wv = (const float*)d_in[7];
    const float* bv = (const float*)d_in[8];
    const float* Wo = (const float*)d_in[9];
    const float* bo = (const float*)d_in[10];
    float* out = (float*)d_out;

    // Workspace: [Qp/ctx 16MB][Kp 32MB][Vp 32MB][W split 4MB] = 84 MB
    float* Qp = (float*)d_ws;
    float* Kp = Qp + (size_t)BB * LQ * EMB;
    float* Vp = Kp + (size_t)BB * LK * EMB;
    unsigned short* Wht = (unsigned short*)(Vp + (size_t)BB * LK * VOUT);
    unsigned short* Wlt = Wht + (size_t)EMB * EMB;

    wsplit_t<<<dim3(EMB / 32, EMB / 32), dim3(32, 8), 0, stream>>>(Wq, Wht, Wlt, EMB, EMB);
    gemm_split<<<(EMB / 128) * (BB * LQ / 128), 256, 0, stream>>>(query, Wht, Wlt, bq, Qp, BB * LQ, EMB, EMB);

    wsplit_t<<<dim3(EMB / 32, VIN / 32), dim3(32, 8), 0, stream>>>(Wk, Wht, Wlt, VIN, EMB);
    gemm_split<<<(EMB / 128) * (BB * LK / 128), 256, 0, stream>>>(key, Wht, Wlt, bk, Kp, BB * LK, EMB, VIN);

    wsplit_t<<<dim3(VOUT / 32, VIN / 32), dim3(32, 8), 0, stream>>>(Wv, Wht, Wlt, VIN, VOUT);
    gemm_split<<<(VOUT / 128) * (BB * LK / 128), 256, 0, stream>>>(value, Wht, Wlt, bv, Vp, BB * LK, VOUT, VIN);

    // Attention (ctx written in-place over Qp; per-block regions disjoint)
    attn_mfma<<<dim3(LQ / 64, NH, BB), 256, 0, stream>>>(Qp, Kp, Vp, Qp);

    wsplit_t<<<dim3(EMB / 32, VOUT / 32), dim3(32, 8), 0, stream>>>(Wo, Wht, Wlt, VOUT, EMB);
    gemm_split<<<(EMB / 128) * (BB * LQ / 128), 256, 0, stream>>>(Qp, Wht, Wlt, bo, out, BB * LQ, EMB, VOUT);
}

// Round 4
// 339.956 us; speedup vs baseline: 2.1866x; 1.0452x over previous
//
#include <hip/hip_runtime.h>

#define EMB  1024
#define VIN  512
#define VOUT 1024
#define NH   16
#define DH   64
#define BB   8
#define LQ   512
#define LK   1024

typedef __attribute__((ext_vector_type(8))) short bf16x8;
typedef __attribute__((ext_vector_type(4))) float f32x4;

typedef const __attribute__((address_space(1))) unsigned int* gptr_t;
typedef __attribute__((address_space(3))) unsigned int* lptr_t;

__device__ __forceinline__ unsigned short f2bf(float x) {
    unsigned int u = __float_as_uint(x);
    u += 0x7FFF + ((u >> 16) & 1);   // RN-even
    return (unsigned short)(u >> 16);
}
__device__ __forceinline__ float bf2f(unsigned short h) {
    return __uint_as_float(((unsigned int)h) << 16);
}

#define SWZ(row, cb) (((row) << 7) + ((cb) ^ (((row) & 7) << 4)))

// ---------------------------------------------------------------------------
// W [K,N] fp32 -> Wht, Wlt [N,K] bf16 hi/lo planes (transposed split).
// ---------------------------------------------------------------------------
__global__ __launch_bounds__(256) void wsplit_t(const float* __restrict__ W,
                                                unsigned short* __restrict__ Wht,
                                                unsigned short* __restrict__ Wlt,
                                                int K, int N)
{
    __shared__ float t[32][33];
    const int n0 = blockIdx.x * 32, k0 = blockIdx.y * 32;
    const int tx = threadIdx.x, ty = threadIdx.y;  // 32 x 8
#pragma unroll
    for (int r = 0; r < 32; r += 8)
        t[ty + r][tx] = W[(size_t)(k0 + ty + r) * N + n0 + tx];
    __syncthreads();
#pragma unroll
    for (int r = 0; r < 32; r += 8) {
        float x = t[tx][ty + r];
        unsigned short h = f2bf(x);
        unsigned short l = f2bf(x - bf2f(h));
        size_t o = (size_t)(n0 + ty + r) * K + k0 + tx;
        Wht[o] = h;
        Wlt[o] = l;
    }
}

// ---------------------------------------------------------------------------
// Split-bf16 MFMA GEMM: C = A(fp32) @ W + bias.
// EPI=0: fp32 C.  EPI=1: bf16 hi/lo planes, natural [row][col].
// EPI=2: bf16 hi/lo planes transposed per head: [(row/LK)*NH + col/64][col%64][row%LK]
// ---------------------------------------------------------------------------
template<int EPI>
__global__ __launch_bounds__(256, 2) void gemm_split(const float* __restrict__ A,
                                                     const unsigned short* __restrict__ Bht,
                                                     const unsigned short* __restrict__ Blt,
                                                     const float* __restrict__ bias,
                                                     float* __restrict__ C,
                                                     unsigned short* __restrict__ Ch,
                                                     unsigned short* __restrict__ Cl,
                                                     int M, int N, int K)
{
    __shared__ unsigned short As_h[128 * 64], As_l[128 * 64];
    __shared__ unsigned short Bs_h[128 * 64], Bs_l[128 * 64];

    const int nbx = N >> 7;
    const int nwg = gridDim.x;
    const int qq  = nwg >> 3;
    const int id  = blockIdx.x;
    const int swz = (id & 7) * qq + (id >> 3);   // XCD-aware (nwg % 8 == 0)
    const int bx = swz % nbx, by = swz / nbx;
    const int m0 = by * 128, n0 = bx * 128;

    const int tid  = threadIdx.x;
    const int lane = tid & 63;
    const int wid  = tid >> 6;
    const int wm = (wid & 1) * 64;
    const int wn = (wid >> 1) * 64;
    const int lr = lane & 15;
    const int lk = lane >> 4;

    f32x4 acc[4][4];
#pragma unroll
    for (int i = 0; i < 4; ++i)
#pragma unroll
        for (int j = 0; j < 4; ++j) acc[i][j] = (f32x4)(0.f);

    float4 ast[8];
    int4   bsth[4], bstl[4];

    const int nt = K >> 6;

    {
#pragma unroll
        for (int r = 0; r < 8; ++r) {
            int i = r * 256 + tid, row = i >> 4, c4 = i & 15;
            ast[r] = *reinterpret_cast<const float4*>(&A[(size_t)(m0 + row) * K + c4 * 4]);
        }
#pragma unroll
        for (int r = 0; r < 4; ++r) {
            int i = r * 256 + tid, row = i >> 3, c16 = i & 7;
            size_t o = (size_t)(n0 + row) * K + c16 * 8;
            bsth[r] = *reinterpret_cast<const int4*>(&Bht[o]);
            bstl[r] = *reinterpret_cast<const int4*>(&Blt[o]);
        }
    }

    for (int t = 0; t < nt; ++t) {
        __syncthreads();
#pragma unroll
        for (int r = 0; r < 8; ++r) {
            int i = r * 256 + tid, row = i >> 4, c4 = i & 15;
            float v[4];
            *reinterpret_cast<float4*>(v) = ast[r];
            ushort h[4], l[4];
#pragma unroll
            for (int j = 0; j < 4; ++j) {
                h[j] = f2bf(v[j]);
                l[j] = f2bf(v[j] - bf2f(h[j]));
            }
            int off = SWZ(row, c4 * 8);
            *reinterpret_cast<uint2*>((char*)As_h + off) = *reinterpret_cast<uint2*>(h);
            *reinterpret_cast<uint2*>((char*)As_l + off) = *reinterpret_cast<uint2*>(l);
        }
#pragma unroll
        for (int r = 0; r < 4; ++r) {
            int i = r * 256 + tid, row = i >> 3, c16 = i & 7;
            int off = SWZ(row, c16 * 16);
            *reinterpret_cast<int4*>((char*)Bs_h + off) = bsth[r];
            *reinterpret_cast<int4*>((char*)Bs_l + off) = bstl[r];
        }
        __syncthreads();

        if (t + 1 < nt) {
            const int k0 = (t + 1) << 6;
#pragma unroll
            for (int r = 0; r < 8; ++r) {
                int i = r * 256 + tid, row = i >> 4, c4 = i & 15;
                ast[r] = *reinterpret_cast<const float4*>(&A[(size_t)(m0 + row) * K + k0 + c4 * 4]);
            }
#pragma unroll
            for (int r = 0; r < 4; ++r) {
                int i = r * 256 + tid, row = i >> 3, c16 = i & 7;
                size_t o = (size_t)(n0 + row) * K + k0 + c16 * 8;
                bsth[r] = *reinterpret_cast<const int4*>(&Bht[o]);
                bstl[r] = *reinterpret_cast<const int4*>(&Blt[o]);
            }
        }

#pragma unroll
        for (int ks = 0; ks < 2; ++ks) {
            bf16x8 ah[4], al[4], bh[4], bl[4];
            const int cb = ks * 64 + lk * 16;
#pragma unroll
            for (int f = 0; f < 4; ++f) {
                int rowA = wm + f * 16 + lr;
                ah[f] = *reinterpret_cast<const bf16x8*>((char*)As_h + SWZ(rowA, cb));
                al[f] = *reinterpret_cast<const bf16x8*>((char*)As_l + SWZ(rowA, cb));
                int rowB = wn + f * 16 + lr;
                bh[f] = *reinterpret_cast<const bf16x8*>((char*)Bs_h + SWZ(rowB, cb));
                bl[f] = *reinterpret_cast<const bf16x8*>((char*)Bs_l + SWZ(rowB, cb));
            }
#pragma unroll
            for (int fm = 0; fm < 4; ++fm)
#pragma unroll
                for (int fn = 0; fn < 4; ++fn) {
                    acc[fm][fn] = __builtin_amdgcn_mfma_f32_16x16x32_bf16(ah[fm], bh[fn], acc[fm][fn], 0, 0, 0);
                    acc[fm][fn] = __builtin_amdgcn_mfma_f32_16x16x32_bf16(ah[fm], bl[fn], acc[fm][fn], 0, 0, 0);
                    acc[fm][fn] = __builtin_amdgcn_mfma_f32_16x16x32_bf16(al[fm], bh[fn], acc[fm][fn], 0, 0, 0);
                }
        }
    }

#pragma unroll
    for (int fn = 0; fn < 4; ++fn) {
        const int col = n0 + wn + fn * 16 + lr;
        const float bv = bias[col];
#pragma unroll
        for (int fm = 0; fm < 4; ++fm) {
            const int row0 = m0 + wm + fm * 16 + lk * 4;
            if constexpr (EPI == 0) {
#pragma unroll
                for (int r = 0; r < 4; ++r)
                    C[(size_t)(row0 + r) * N + col] = acc[fm][fn][r] + bv;
            } else if constexpr (EPI == 1) {
#pragma unroll
                for (int r = 0; r < 4; ++r) {
                    float x = acc[fm][fn][r] + bv;
                    ushort h = f2bf(x);
                    ushort l = f2bf(x - bf2f(h));
                    size_t o = (size_t)(row0 + r) * N + col;
                    Ch[o] = h;
                    Cl[o] = l;
                }
            } else {
                // transposed per-head: plane row = (b*NH + head)*64 + dv, col = key
                ushort h4[4], l4[4];
#pragma unroll
                for (int r = 0; r < 4; ++r) {
                    float x = acc[fm][fn][r] + bv;
                    h4[r] = f2bf(x);
                    l4[r] = f2bf(x - bf2f(h4[r]));
                }
                size_t o = (((size_t)((row0 >> 10) * NH + (col >> 6)) * 64 + (col & 63)) << 10) + (row0 & 1023);
                *reinterpret_cast<uint2*>(&Ch[o]) = *reinterpret_cast<uint2*>(h4);
                *reinterpret_cast<uint2*>(&Cl[o]) = *reinterpret_cast<uint2*>(l4);
            }
        }
    }
}

// ---------------------------------------------------------------------------
// Stage a 64-row x 128B tile (row stride 1024 elements) into linear LDS via
// global_load_lds, source pre-swizzled so SWZ reads land correctly.
// All 64 lanes of one wave issue 8 x 16B.
// ---------------------------------------------------------------------------
__device__ __forceinline__ void stage64(const unsigned short* g0, unsigned short* l0, int lane)
{
#pragma unroll
    for (int r = 0; r < 8; ++r) {
        int row  = r * 8 + (lane >> 3);
        int colb = ((lane & 7) << 4) ^ ((row & 7) << 4);
        const unsigned short* src = g0 + ((size_t)row << 10) + (colb >> 1);
        __builtin_amdgcn_global_load_lds((gptr_t)src, (lptr_t)(l0 + r * 512), 16, 0, 0);
    }
}

// ---------------------------------------------------------------------------
// MFMA flash attention, split-bf16 both contractions; K/V pre-split in HBM.
// 1-D grid, XCD-grouped decode: 8 q-tiles of one (b,h) on one XCD.
// ctx aliases Qp (block reads its exact Q region before any write).
// ---------------------------------------------------------------------------
__global__ __launch_bounds__(256, 2) void attn_mfma(const float* Qp,
                                                    const unsigned short* __restrict__ Kh,
                                                    const unsigned short* __restrict__ Kl,
                                                    const unsigned short* __restrict__ Vth,
                                                    const unsigned short* __restrict__ Vtl,
                                                    float* ctx)
{
    const int id  = blockIdx.x;
    const int qt  = (id >> 3) & 7;
    const int grp = (id & 7) | ((id >> 6) << 3);   // 0..127, same-XCD groups
    const int h = grp & 15, b = grp >> 4;

    const int tid  = threadIdx.x;
    const int lane = tid & 63;
    const int w    = tid >> 6;
    const int lr   = lane & 15;
    const int lk   = lane >> 4;

    __shared__ unsigned short KVs[2][4][4096];            // [buf][Kh,Kl,Vh,Vl][64x64]
    __shared__ unsigned short Ps_h[4][1024], Ps_l[4][1024];

    // --- Q fragments (scaled + split), rows w*16 + lr -----------------------
    bf16x8 qh[2], ql[2];
    {
        const float scale = 0.125f;  // 1/sqrt(64)
        const float* qrow = &Qp[(size_t)(b * LQ + qt * 64 + w * 16 + lr) * EMB + h * DH];
#pragma unroll
        for (int ks = 0; ks < 2; ++ks) {
            float v[8];
            *reinterpret_cast<float4*>(v)     = *reinterpret_cast<const float4*>(&qrow[ks * 32 + lk * 8]);
            *reinterpret_cast<float4*>(v + 4) = *reinterpret_cast<const float4*>(&qrow[ks * 32 + lk * 8 + 4]);
            ushort hh[8], ll[8];
#pragma unroll
            for (int e = 0; e < 8; ++e) {
                float x = v[e] * scale;
                hh[e] = f2bf(x);
                ll[e] = f2bf(x - bf2f(hh[e]));
            }
            qh[ks] = *reinterpret_cast<bf16x8*>(hh);
            ql[ks] = *reinterpret_cast<bf16x8*>(ll);
        }
    }

    // global tile bases (row stride 1024 elements for all four planes)
    const unsigned short* Kh0 = Kh + ((size_t)(b * LK) << 10) + h * DH;
    const unsigned short* Kl0 = Kl + ((size_t)(b * LK) << 10) + h * DH;
    const unsigned short* Vh0 = Vth + ((size_t)(grp * 64) << 10);
    const unsigned short* Vl0 = Vtl + ((size_t)(grp * 64) << 10);

    // prefetch tile 0 (wave w stages plane w)
    {
        unsigned short* L = KVs[0][w];
        if      (w == 0) stage64(Kh0, L, lane);
        else if (w == 1) stage64(Kl0, L, lane);
        else if (w == 2) stage64(Vh0, L, lane);
        else             stage64(Vl0, L, lane);
    }

    float m[4], lsum[4];
    f32x4 acc[4];
#pragma unroll
    for (int r = 0; r < 4; ++r) { m[r] = -1e30f; lsum[r] = 0.f; }
#pragma unroll
    for (int f = 0; f < 4; ++f) acc[f] = (f32x4)(0.f);

    for (int kt = 0; kt < LK / 64; ++kt) {
        const int cur = kt & 1;
        __syncthreads();   // drains vmcnt: tile kt resident; prev compute done

        if (kt + 1 < LK / 64) {
            const size_t koff = ((size_t)(kt + 1) * 64);
            unsigned short* L = KVs[cur ^ 1][w];
            if      (w == 0) stage64(Kh0 + (koff << 10), L, lane);
            else if (w == 1) stage64(Kl0 + (koff << 10), L, lane);
            else if (w == 2) stage64(Vh0 + koff, L, lane);
            else             stage64(Vl0 + koff, L, lane);
        }

        const char* KsH = (const char*)KVs[cur][0];
        const char* KsL = (const char*)KVs[cur][1];
        const char* VsH = (const char*)KVs[cur][2];
        const char* VsL = (const char*)KVs[cur][3];

        // QK^T -----------------------------------------------------------
        f32x4 s[4];
#pragma unroll
        for (int fn = 0; fn < 4; ++fn) s[fn] = (f32x4)(0.f);
#pragma unroll
        for (int ks = 0; ks < 2; ++ks) {
            const int cb = ks * 64 + lk * 16;
#pragma unroll
            for (int fn = 0; fn < 4; ++fn) {
                bf16x8 kh = *reinterpret_cast<const bf16x8*>(KsH + SWZ(fn * 16 + lr, cb));
                bf16x8 kl = *reinterpret_cast<const bf16x8*>(KsL + SWZ(fn * 16 + lr, cb));
                s[fn] = __builtin_amdgcn_mfma_f32_16x16x32_bf16(qh[ks], kh, s[fn], 0, 0, 0);
                s[fn] = __builtin_amdgcn_mfma_f32_16x16x32_bf16(qh[ks], kl, s[fn], 0, 0, 0);
                s[fn] = __builtin_amdgcn_mfma_f32_16x16x32_bf16(ql[ks], kh, s[fn], 0, 0, 0);
            }
        }

        // online softmax -----------------------------------------------------
#pragma unroll
        for (int r = 0; r < 4; ++r) {
            float mx = fmaxf(fmaxf(s[0][r], s[1][r]), fmaxf(s[2][r], s[3][r]));
            mx = fmaxf(mx, __shfl_xor(mx, 1));
            mx = fmaxf(mx, __shfl_xor(mx, 2));
            mx = fmaxf(mx, __shfl_xor(mx, 4));
            mx = fmaxf(mx, __shfl_xor(mx, 8));
            float mnew = fmaxf(m[r], mx);
            float corr = __expf(m[r] - mnew);
            m[r] = mnew;
            float rs = 0.f;
#pragma unroll
            for (int fn = 0; fn < 4; ++fn) {
                float p = __expf(s[fn][r] - mnew);
                s[fn][r] = p;
                rs += p;
            }
            rs += __shfl_xor(rs, 1);
            rs += __shfl_xor(rs, 2);
            rs += __shfl_xor(rs, 4);
            rs += __shfl_xor(rs, 8);
            lsum[r] = lsum[r] * corr + rs;
#pragma unroll
            for (int f = 0; f < 4; ++f) acc[f][r] *= corr;
        }

        // P (split) -> wave-private LDS [q][key] ----------------------------
#pragma unroll
        for (int fn = 0; fn < 4; ++fn)
#pragma unroll
            for (int r = 0; r < 4; ++r) {
                float p = s[fn][r];
                ushort ph = f2bf(p);
                ushort pl = f2bf(p - bf2f(ph));
                int q = lk * 4 + r, cb = 2 * (fn * 16 + lr);
                *reinterpret_cast<ushort*>((char*)Ps_h[w] + SWZ(q, cb)) = ph;
                *reinterpret_cast<ushort*>((char*)Ps_l[w] + SWZ(q, cb)) = pl;
            }

        // PV ---------------------------------------------------------------
#pragma unroll
        for (int ks = 0; ks < 2; ++ks) {
            const int cb = ks * 64 + lk * 16;
            bf16x8 pa = *reinterpret_cast<const bf16x8*>((char*)Ps_h[w] + SWZ(lr, cb));
            bf16x8 pb = *reinterpret_cast<const bf16x8*>((char*)Ps_l[w] + SWZ(lr, cb));
#pragma unroll
            for (int f = 0; f < 4; ++f) {
                bf16x8 vh = *reinterpret_cast<const bf16x8*>(VsH + SWZ(f * 16 + lr, cb));
                bf16x8 vl = *reinterpret_cast<const bf16x8*>(VsL + SWZ(f * 16 + lr, cb));
                acc[f] = __builtin_amdgcn_mfma_f32_16x16x32_bf16(pa, vh, acc[f], 0, 0, 0);
                acc[f] = __builtin_amdgcn_mfma_f32_16x16x32_bf16(pa, vl, acc[f], 0, 0, 0);
                acc[f] = __builtin_amdgcn_mfma_f32_16x16x32_bf16(pb, vh, acc[f], 0, 0, 0);
            }
        }
    }

    // epilogue ---------------------------------------------------------------
#pragma unroll
    for (int r = 0; r < 4; ++r) {
        float inv = 1.f / lsum[r];
        float* crow = &ctx[(size_t)(b * LQ + qt * 64 + w * 16 + lk * 4 + r) * VOUT + h * DH];
#pragma unroll
        for (int f = 0; f < 4; ++f)
            crow[f * 16 + lr] = acc[f][r] * inv;
    }
}

extern "C" void kernel_launch(void* const* d_in, const int* in_sizes, int n_in,
                              void* d_out, int out_size, void* d_ws, size_t ws_size,
                              hipStream_t stream)
{
    const float* query = (const float*)d_in[0];
    const float* key   = (const float*)d_in[1];
    const float* value = (const float*)d_in[2];
    const float* Wq = (const float*)d_in[3];
    const float* bq = (const float*)d_in[4];
    const float* Wk = (const float*)d_in[5];
    const float* bk = (const float*)d_in[6];
    const float* Wv = (const float*)d_in[7];
    const float* bv = (const float*)d_in[8];
    const float* Wo = (const float*)d_in[9];
    const float* bo = (const float*)d_in[10];
    float* out = (float*)d_out;

    // Workspace: Qp/ctx 16MB | Kh 16 | Kl 16 | Vth 16 | Vtl 16 | Wsplit 4 = 84MB
    float* Qp = (float*)d_ws;
    unsigned short* Kh  = (unsigned short*)(Qp + (size_t)BB * LQ * EMB);
    unsigned short* Kl  = Kh  + (size_t)BB * LK * EMB;
    unsigned short* Vth = Kl  + (size_t)BB * LK * EMB;
    unsigned short* Vtl = Vth + (size_t)BB * NH * DH * LK;
    unsigned short* Wht = Vtl + (size_t)BB * NH * DH * LK;
    unsigned short* Wlt = Wht + (size_t)EMB * EMB;

    wsplit_t<<<dim3(EMB / 32, EMB / 32), dim3(32, 8), 0, stream>>>(Wq, Wht, Wlt, EMB, EMB);
    gemm_split<0><<<(EMB / 128) * (BB * LQ / 128), 256, 0, stream>>>(query, Wht, Wlt, bq, Qp, nullptr, nullptr, BB * LQ, EMB, EMB);

    wsplit_t<<<dim3(EMB / 32, VIN / 32), dim3(32, 8), 0, stream>>>(Wk, Wht, Wlt, VIN, EMB);
    gemm_split<1><<<(EMB / 128) * (BB * LK / 128), 256, 0, stream>>>(key, Wht, Wlt, bk, nullptr, Kh, Kl, BB * LK, EMB, VIN);

    wsplit_t<<<dim3(VOUT / 32, VIN / 32), dim3(32, 8), 0, stream>>>(Wv, Wht, Wlt, VIN, VOUT);
    gemm_split<2><<<(VOUT / 128) * (BB * LK / 128), 256, 0, stream>>>(value, Wht, Wlt, bv, nullptr, Vth, Vtl, BB * LK, VOUT, VIN);

    attn_mfma<<<LQ / 64 * NH * BB, 256, 0, stream>>>(Qp, Kh, Kl, Vth, Vtl, Qp);

    wsplit_t<<<dim3(EMB / 32, VOUT / 32), dim3(32, 8), 0, stream>>>(Wo, Wht, Wlt, VOUT, EMB);
    gemm_split<0><<<(EMB / 128) * (BB * LQ / 128), 256, 0, stream>>>(Qp, Wht, Wlt, bo, out, nullptr, nullptr, BB * LQ, EMB, VOUT);
}